// Round 13
// baseline (171.538 us; speedup 1.0000x reference)
//
#include <hip/hip_runtime.h>

#define N_NODES 50000
#define N_EDGES 800000
#define NB 196  // ceil(N_NODES / 256)

typedef unsigned int uint;
typedef short bf16x8 __attribute__((ext_vector_type(8)));
typedef float f32x4 __attribute__((ext_vector_type(4)));
typedef uint uint4v __attribute__((ext_vector_type(4)));  // native vec for nontemporal builtins

__device__ __forceinline__ ushort f2bf(float f) {
    union { float f; uint u; } v; v.f = f;
    uint r = (v.u + 0x7FFFu + ((v.u >> 16) & 1u)) >> 16;  // RNE
    return (ushort)r;
}
__device__ __forceinline__ float bf_lo(uint u) { return __uint_as_float(u << 16); }
__device__ __forceinline__ float bf_hi(uint u) { return __uint_as_float(u & 0xFFFF0000u); }

// ---------- fused prep: [0,3125) tobf16(emb) | [3125,3321) zero counts | [3321,3386) W12/bvec ----------
__global__ void k_prep(const float* __restrict__ emb, const float* __restrict__ W1,
                       const float* __restrict__ W2, const float* __restrict__ b1,
                       uint* __restrict__ emb_h, ushort* __restrict__ W12t,
                       float* __restrict__ bvec, int* __restrict__ counts) {
    int b = blockIdx.x;
    int tid = threadIdx.x;
    if (b < 3125) {                       // emb -> bf16 (8 floats/thread)
        int t = b * 256 + tid;
        const float4* i4 = (const float4*)emb + (size_t)t * 2;
        float4 v0 = i4[0], v1 = i4[1];
        uint4 o;
        o.x = (uint)f2bf(v0.x) | ((uint)f2bf(v0.y) << 16);
        o.y = (uint)f2bf(v0.z) | ((uint)f2bf(v0.w) << 16);
        o.z = (uint)f2bf(v1.x) | ((uint)f2bf(v1.y) << 16);
        o.w = (uint)f2bf(v1.z) | ((uint)f2bf(v1.w) << 16);
        ((uint4*)emb_h)[t] = o;
    } else if (b < 3125 + NB) {           // zero counts
        int i = (b - 3125) * 256 + tid;
        if (i < N_NODES) counts[i] = 0;
    } else {                              // W12t[n][k] = bf16(sum_m W1[k][m]W2[m][n]); k=128 -> bvec
        int k = (b - (3125 + NB)) * 2 + (tid >> 7);
        int n = tid & 127;
        float s = 0.f;
        if (k < 128) {
            for (int m = 0; m < 256; ++m) s = fmaf(W1[(size_t)k * 256 + m], W2[(size_t)m * 128 + n], s);
            W12t[(size_t)n * 128 + k] = f2bf(s);
        } else if (k == 128) {
            for (int m = 0; m < 256; ++m) s = fmaf(b1[m], W2[(size_t)m * 128 + n], s);
            bvec[n] = s;
        }
    }
}

// ---------- degree / CSR build ----------

__global__ void k_histrank(const int* __restrict__ dst, int* __restrict__ counts,
                           ushort* __restrict__ rank) {
    int e = blockIdx.x * 256 + threadIdx.x;
    if (e < N_EDGES) rank[e] = (ushort)atomicAdd(&counts[dst[e]], 1);
}

__global__ void k_blocksum(const int* __restrict__ counts, int* __restrict__ bsum) {
    __shared__ int lds[256];
    int t = threadIdx.x;
    int i = blockIdx.x * 256 + t;
    int v = (i < N_NODES) ? counts[i] : 0;
    lds[t] = v;
    __syncthreads();
    for (int off = 128; off > 0; off >>= 1) {
        if (t < off) lds[t] += lds[t + off];
        __syncthreads();
    }
    if (t == 0) bsum[blockIdx.x] = lds[0];
}

__global__ void k_scanb(const int* __restrict__ bsum, int* __restrict__ boff) {
    __shared__ int lds[256];
    int t = threadIdx.x;
    int v = (t < NB) ? bsum[t] : 0;
    lds[t] = v;
    __syncthreads();
    for (int off = 1; off < 256; off <<= 1) {
        int o = (t >= off) ? lds[t - off] : 0;
        __syncthreads();
        lds[t] += o;
        __syncthreads();
    }
    if (t < NB) boff[t] = lds[t] - v;  // exclusive
}

__global__ void k_scatter_rp(const int* __restrict__ counts, const int* __restrict__ boff,
                             int* __restrict__ row_ptr, float* __restrict__ dinv) {
    __shared__ int lds[256];
    int t = threadIdx.x;
    int i = blockIdx.x * 256 + t;
    int v = (i < N_NODES) ? counts[i] : 0;
    lds[t] = v;
    __syncthreads();
    for (int off = 1; off < 256; off <<= 1) {
        int o = (t >= off) ? lds[t - off] : 0;
        __syncthreads();
        lds[t] += o;
        __syncthreads();
    }
    if (i < N_NODES) {
        row_ptr[i] = boff[blockIdx.x] + lds[t] - v;
        dinv[i] = rsqrtf((float)(v + 1));  // +1 self-loop
    }
    if (i == 0) row_ptr[N_NODES] = N_EDGES;
}

// atomic-free CSR fill; entry packs (src<<16) | bf16(dinv[src]).
__global__ void k_fillr(const int* __restrict__ src, const int* __restrict__ dst,
                        const ushort* __restrict__ rank, const int* __restrict__ row_ptr,
                        const float* __restrict__ dinv, uint* __restrict__ csr) {
    int e = blockIdx.x * 256 + threadIdx.x;
    if (e >= N_EDGES) return;
    int s = src[e];
    int pos = row_ptr[dst[e]] + (int)rank[e];
    csr[pos] = ((uint)s << 16) | (uint)f2bf(dinv[s]);
}

// ---------- shared gather core: one wave aggregates one node's 128-feat bf16 row ----------
// 4 quarter-waves x 8-deep unroll = 32 source rows in flight per wave.
// Returns o[8] (fp32 feats fl*8..fl*8+8) valid in q==0 lanes, and sc (sum of coefs).
__device__ __forceinline__ void gather_core(const uint* __restrict__ xh,
                                            const uint* __restrict__ csr,
                                            int beg, int end, int node, float dd,
                                            int q, int fl, float o[8], float& scn) {
    const uint4* xb = (const uint4*)xh;
    float a[8];
    #pragma unroll
    for (int i = 0; i < 8; ++i) a[i] = 0.f;
    float sc = 0.f;

    for (int j = beg + q; j < end; j += 32) {
        uint e0 = csr[j];
        uint def = e0 & 0xFFFF0000u;   // c=0, valid src
        uint e[8];
        e[0] = e0;
        #pragma unroll
        for (int i = 1; i < 8; ++i) {
            int ji = j + 4 * i;
            e[i] = (ji < end) ? csr[ji] : def;
        }
        uint4 u[8];
        #pragma unroll
        for (int i = 0; i < 8; ++i) u[i] = xb[(size_t)(e[i] >> 16) * 16 + fl];
        #pragma unroll
        for (int i = 0; i < 8; ++i) {
            float c = bf_lo(e[i]);
            sc += c;
            a[0] = fmaf(c, bf_lo(u[i].x), a[0]); a[1] = fmaf(c, bf_hi(u[i].x), a[1]);
            a[2] = fmaf(c, bf_lo(u[i].y), a[2]); a[3] = fmaf(c, bf_hi(u[i].y), a[3]);
            a[4] = fmaf(c, bf_lo(u[i].z), a[4]); a[5] = fmaf(c, bf_hi(u[i].z), a[5]);
            a[6] = fmaf(c, bf_lo(u[i].w), a[6]); a[7] = fmaf(c, bf_hi(u[i].w), a[7]);
        }
    }
    #pragma unroll
    for (int off = 16; off < 64; off <<= 1) {
        #pragma unroll
        for (int i = 0; i < 8; ++i) a[i] += __shfl_xor(a[i], off);
        sc += __shfl_xor(sc, off);
    }
    float dd2 = dd * dd;
    const uint4* xs = (const uint4*)xh + (size_t)node * 16 + fl;
    uint4 u = *xs;
    float s[8] = { bf_lo(u.x), bf_hi(u.x), bf_lo(u.y), bf_hi(u.y),
                   bf_lo(u.z), bf_hi(u.z), bf_lo(u.w), bf_hi(u.w) };
    #pragma unroll
    for (int i = 0; i < 8; ++i) o[i] = fmaf(dd, a[i], dd2 * s[i]);
    scn = fmaf(dd, sc, dd2);
}

// ---------- gather1: G = bf16(Agg(emb)), nontemporal output ----------
__global__ void k_gather1(const uint* __restrict__ xh, const uint* __restrict__ csr,
                          const int* __restrict__ rp, const float* __restrict__ dinv,
                          uint* __restrict__ outp) {
    int node = blockIdx.x * 4 + (threadIdx.x >> 6);
    int lane = threadIdx.x & 63;
    int q = lane >> 4, fl = lane & 15;
    int beg = rp[node], end = rp[node + 1];
    float o[8], scn;
    gather_core(xh, csr, beg, end, node, dinv[node], q, fl, o, scn);
    if (q == 0) {
        uint4v p;
        p.x = (uint)f2bf(o[0]) | ((uint)f2bf(o[1]) << 16);
        p.y = (uint)f2bf(o[2]) | ((uint)f2bf(o[3]) << 16);
        p.z = (uint)f2bf(o[4]) | ((uint)f2bf(o[5]) << 16);
        p.w = (uint)f2bf(o[6]) | ((uint)f2bf(o[7]) << 16);
        __builtin_nontemporal_store(p, (uint4v*)outp + (size_t)node * 16 + fl);
    }
}

// ---------- fused gather2 + MFMA GEMM + epilogue ----------
// 16 waves/block, wave w aggregates node blockIdx*16+w -> bf16 row in LDS (XOR-swizzled).
// Then waves 0-7: out[16x128] = rows @ W12t + nvec*bvec + b2 via mfma_16x16x32_bf16.
__global__ void __launch_bounds__(1024)
k_gather_gemm(const uint* __restrict__ xh, const uint* __restrict__ csr,
              const int* __restrict__ rp, const float* __restrict__ dinv,
              const ushort* __restrict__ Wt, const float* __restrict__ bvec,
              const float* __restrict__ b2, float* __restrict__ out) {
    __shared__ ushort rows[16 * 128];   // 4KB, swizzle: ushort idx ^= (row&7)<<3
    __shared__ float nvl[16];
    const int w = threadIdx.x >> 6;
    const int lane = threadIdx.x & 63;
    const int node = blockIdx.x * 16 + w;
    const int q = lane >> 4, fl = lane & 15;
    const int beg = rp[node], end = rp[node + 1];

    float o[8], scn;
    gather_core(xh, csr, beg, end, node, dinv[node], q, fl, o, scn);
    if (q == 0) {
        uint4 p;
        p.x = (uint)f2bf(o[0]) | ((uint)f2bf(o[1]) << 16);
        p.y = (uint)f2bf(o[2]) | ((uint)f2bf(o[3]) << 16);
        p.z = (uint)f2bf(o[4]) | ((uint)f2bf(o[5]) << 16);
        p.w = (uint)f2bf(o[6]) | ((uint)f2bf(o[7]) << 16);
        int idx = (w * 128 + fl * 8) ^ ((w & 7) << 3);
        *(uint4*)&rows[idx] = p;
        if (fl == 0) nvl[w] = scn;
    }
    __syncthreads();

    if (w < 8) {
        const int col = w * 16 + (lane & 15);
        const int ksub = (lane >> 4) * 8;
        const int row = lane & 15;
        f32x4 acc = (f32x4){0.f, 0.f, 0.f, 0.f};
        #pragma unroll
        for (int kc = 0; kc < 4; ++kc) {
            int idxr = (row * 128 + kc * 32 + ksub) ^ ((row & 7) << 3);
            bf16x8 af = *(const bf16x8*)&rows[idxr];
            bf16x8 bf = *(const bf16x8*)(Wt + (size_t)col * 128 + kc * 32 + ksub);
            acc = __builtin_amdgcn_mfma_f32_16x16x32_bf16(af, bf, acc, 0, 0, 0);
        }
        const int rb = (lane >> 4) * 4;
        float bv = bvec[col], bb = b2[col];
        #pragma unroll
        for (int e = 0; e < 4; ++e) {
            float nv = nvl[rb + e];
            out[(size_t)(blockIdx.x * 16 + rb + e) * 128 + col] = acc[e] + nv * bv + bb;
        }
    }
}

extern "C" void kernel_launch(void* const* d_in, const int* in_sizes, int n_in,
                              void* d_out, int out_size, void* d_ws, size_t ws_size,
                              hipStream_t stream) {
    const float* emb = (const float*)d_in[0];   // [50000][128]
    const float* W1  = (const float*)d_in[1];   // [128][256]
    const float* b1  = (const float*)d_in[2];   // [256]
    const float* W2  = (const float*)d_in[3];   // [256][128]
    const float* b2  = (const float*)d_in[4];   // [128]
    const int*   ei  = (const int*)d_in[5];     // [2][800000]
    const int* src = ei;
    const int* dst = ei + N_EDGES;

    char* ws = (char*)d_ws;
    float*  dinv    = (float*) (ws);                    // 200 KB
    int*    counts  = (int*)   (ws + (256ull << 10));   // 200 KB
    int*    row_ptr = (int*)   (ws + (512ull << 10));   // 200 KB + 4
    int*    bsum    = (int*)   (ws + (768ull << 10));   // 784 B
    int*    boff    = (int*)   (ws + (772ull << 10));   // 784 B
    ushort* rank    = (ushort*)(ws + (1ull << 20));     // 1.6 MB  (1..2.6)
    uint*   csr     = (uint*)  (ws + (3ull << 20));     // 3.2 MB  (3..6.2)
    ushort* W12t    = (ushort*)(ws + (6656ull << 10));  // 32 KB   (6.5MB)
    float*  bvec    = (float*) (ws + (6720ull << 10));  // 512 B
    uint*   emb_h   = (uint*)  (ws + (7ull  << 20));    // 12.8 MB (7..19.8)
    uint*   G       = (uint*)  (ws + (20ull << 20));    // 12.8 MB (20..32.8)
    float*  out     = (float*)d_out;

    // fused prep: emb->bf16, zero counts, W12t/bvec
    k_prep<<<3386, 256, 0, stream>>>(emb, W1, W2, b1, emb_h, W12t, bvec, counts);

    // CSR build + normalization
    k_histrank<<<(N_EDGES + 255) / 256, 256, 0, stream>>>(dst, counts, rank);
    k_blocksum<<<NB, 256, 0, stream>>>(counts, bsum);
    k_scanb<<<1, 256, 0, stream>>>(bsum, boff);
    k_scatter_rp<<<NB, 256, 0, stream>>>(counts, boff, row_ptr, dinv);
    k_fillr<<<(N_EDGES + 255) / 256, 256, 0, stream>>>(src, dst, rank, row_ptr, dinv, csr);

    // out = (N^2 emb) @ (W1W2) + (N·1)(b1W2) + b2
    k_gather1<<<12500, 256, 0, stream>>>(emb_h, csr, row_ptr, dinv, G);
    k_gather_gemm<<<3125, 1024, 0, stream>>>(G, csr, row_ptr, dinv,
                                             (const ushort*)W12t, bvec, b2, out);
}